// Round 20
// baseline (208.660 us; speedup 1.0000x reference)
//
#include <hip/hip_runtime.h>
#include <hip/hip_fp16.h>

// Shapes (fixed by the reference setup_inputs)
#define NB 2
#define NH 16
#define NS 2048
#define ND 64

typedef __attribute__((ext_vector_type(8))) _Float16 half8;
typedef __attribute__((ext_vector_type(4))) _Float16 half4;
typedef __attribute__((ext_vector_type(4))) float float4v;

static constexpr int NE = NB * NH * NS * ND;     // 4,194,304 elems per tensor
static constexpr int TPB = 512;                  // 8 waves

// LDS-only workgroup barrier (R14-verified, -45us vs __syncthreads):
// syncs LDS writes across waves WITHOUT the vmcnt(0) drain.
__device__ __forceinline__ void wg_barrier_lds() {
    asm volatile("s_waitcnt lgkmcnt(0)" ::: "memory");
    __builtin_amdgcn_s_barrier();
    __builtin_amdgcn_sched_barrier(0);
}

// ---------------------------------------------------------------------------
// Fused prep kernel (R15/R16-verified): three independent streams, ONE launch.
// kr6 (per bh): [kt][oct=d/8][key%16][d%8] -> QK^T B-frag load is 1024B contig.
// v4  (per bh): [kt][dblk=d/16][kq][d%16][key%4] -> PV A-frag load 512B contig.
// ---------------------------------------------------------------------------
static constexpr int ROPE_BLKS = (NE / 2) / 256;          // 8192
static constexpr int VT_BLKS   = NE / 256;                // 16384
static constexpr int MP_BLKS   = (NB * NS * NS) / 256;    // 32768

__global__ void prep_kernel(const float* __restrict__ q,
                            const float* __restrict__ k,
                            const float* __restrict__ v,
                            const int* __restrict__ mask,
                            _Float16* __restrict__ qr,
                            _Float16* __restrict__ kr6,
                            _Float16* __restrict__ v4,
                            unsigned int* __restrict__ mp) {
    int blk = blockIdx.x;
    if (blk < ROPE_BLKS) {
        int idx = blk * 256 + threadIdx.x;          // over NE/2
        int i   = idx & 31;        // freq index (d pair = 2i, 2i+1)
        int row = idx >> 5;        // (b*NH + h)*NS + s
        int s   = row & (NS - 1);
        int bh  = row >> 11;

        float inv_freq = expf((float)i * -0.2878231366242710f);  // 10000^(-i/32)
        float ang = (float)s * inv_freq;
        float sn, cs;
        sincosf(ang, &sn, &cs);

        size_t base = (size_t)row * ND + 2 * i;
        float q0 = q[base], q1 = q[base + 1];
        float k0 = k[base], k1 = k[base + 1];
        qr[base]     = (_Float16)(q0 * cs - q1 * sn);
        qr[base + 1] = (_Float16)(q1 * cs + q0 * sn);

        int oct = i >> 2;
        int j0  = (2 * i) & 7;
        size_t t6 = ((size_t)(bh * 128 + (s >> 4)) * 8 + oct) * 128 + (s & 15) * 8 + j0;
        kr6[t6]     = (_Float16)(k0 * cs - k1 * sn);
        kr6[t6 + 1] = (_Float16)(k1 * cs + k0 * sn);
    } else if (blk < ROPE_BLKS + VT_BLKS) {
        int idx = (blk - ROPE_BLKS) * 256 + threadIdx.x;   // linear v4 index
        int j    = idx & 3;            // key%4
        int lm   = (idx >> 2) & 15;    // d%16
        int kq   = (idx >> 6) & 3;     // (key%16)/4
        int dblk = (idx >> 8) & 3;
        int kt   = (idx >> 10) & 127;
        int bh   = idx >> 17;
        int key  = kt * 16 + kq * 4 + j;
        int d    = dblk * 16 + lm;
        v4[idx] = (_Float16)v[((size_t)bh * NS + key) * ND + d];
    } else {
        size_t idx = (size_t)(blk - ROPE_BLKS - VT_BLKS) * 256 + threadIdx.x;
        unsigned long long bal = __ballot(mask[idx] != 0);
        int l = threadIdx.x & 63;
        if (l == 0)       mp[idx >> 5] = (unsigned int)bal;
        else if (l == 32) mp[idx >> 5] = (unsigned int)(bal >> 32);
    }
}

// ---------------------------------------------------------------------------
// Attention kernel (R20): R19 byte-identical EXCEPT score stores are PLAIN
// (not nt). Tests the (1KB-contiguous, plain) cell of the {width x policy}
// matrix: R15's plain-store loss was confounded with 64B partial-line
// segments (write-allocate churn); full-line 1KB plain stores need no
// allocate and can ride the fill kernel's 6.6 TB/s write-combine path.
// Operand working set (kr6+v4, 512KB/bh) displaced from L2 falls to L3.
// DETERMINISM: no LDS atomics/init; unique-owner LDS writes before
// barrier; fixed-order final sums.
// ---------------------------------------------------------------------------
static constexpr int TPH    = 264;        // trans pitch in halfs (528 B)
static constexpr int WSLICE = 16 * TPH;   // halfs per wave slice (8448 B)

__global__ __launch_bounds__(TPB, 4)
void attn_reg_kernel(const _Float16* __restrict__ qr,
                     const _Float16* __restrict__ kr6,
                     const _Float16* __restrict__ v4,
                     const unsigned int* __restrict__ mp,
                     float* __restrict__ out,
                     float* __restrict__ score) {
    __shared__ unsigned int maskb[16 * 64];        // 4 KB
    __shared__ float        sums8[8][16];          // 512 B
    __shared__ _Float16     pool[8 * WSLICE];      // 67,584 B: trans, then outb alias

    // XCD-aware bijective swizzle: 4096 WGs -> contiguous 512 per XCD
    int wgid = (blockIdx.x & 7) * 512 + (blockIdx.x >> 3);
    int qt = wgid & 127;
    int bh = wgid >> 7;
    int b  = bh >> 4;
    int q0 = qt * 16;

    int tid = threadIdx.x;
    int w   = tid >> 6;
    int l   = tid & 63;
    int lm  = l & 15;
    int lp  = l >> 4;

    {
        const unsigned int* mrow = mp + ((size_t)b * NS + q0) * 64;
        for (int i = tid; i < 16 * 64; i += TPB) maskb[i] = mrow[i];
    }

    // Q B-fragment (col n = q = lm, k-slice d = lp*8+[0..7] (+32))
    const _Float16* qrow = qr + ((size_t)bh * NS + q0 + lm) * ND;
    half8 a0 = *(const half8*)(qrow + lp * 8);
    half8 a1 = *(const half8*)(qrow + 32 + lp * 8);
    const _Float16* k6 = kr6 + (size_t)bh * 128 * 1024;
    _Float16* tw = pool + w * WSLICE;               // wave-private trans slice
    wg_barrier_lds();                      // maskb visible

    // ---- phase 1: fused {QK^T -> exp -> stage fp16 | PV MFMA} + row sums ----
    float4v ac0 = {0.f, 0.f, 0.f, 0.f};
    float4v ac1 = {0.f, 0.f, 0.f, 0.f};
    float4v ac2 = {0.f, 0.f, 0.f, 0.f};
    float4v ac3 = {0.f, 0.f, 0.f, 0.f};
    const _Float16* vb = v4 + (size_t)bh * 128 * 1024 + l * 4;
    float ps = 0.0f;
#pragma unroll
    for (int t = 0; t < 16; ++t) {
        int kt = w * 16 + t;
        const _Float16* kp = k6 + (size_t)kt * 1024 + l * 8;
        half8 b0 = *(const half8*)(kp);          // 1024B contiguous wave-load
        half8 b1 = *(const half8*)(kp + 512);
        float4v acc = {0.f, 0.f, 0.f, 0.f};
        acc = __builtin_amdgcn_mfma_f32_16x16x32_f16(b0, a0, acc, 0, 0, 0);  // A=K rows
        acc = __builtin_amdgcn_mfma_f32_16x16x32_f16(b1, a1, acc, 0, 0, 0);  // B=Q rows
        // acc[r]: key = kt*16 + lp*4 + r, q = q0 + lm
        int keyb = kt * 16 + lp * 4;
        unsigned int mw = maskb[lm * 64 + (keyb >> 5)];
        int bit0 = keyb & 31;
        half4 ep;
#pragma unroll
        for (int r = 0; r < 4; ++r) {
            float ev = ((mw >> (bit0 + r)) & 1u) ? __expf(acc[r] * 0.125f) : 0.0f;
            ps += ev;
            ep[r] = (_Float16)ev;
        }
        // stage e fp16 into wave-private trans (ds_write_b64)
        *(half4*)(tw + lm * TPH + t * 16 + lp * 4) = ep;

        // PV for this key-subtile
        const _Float16* vp = vb + (size_t)kt * 1024;
        half4 af0 = *(const half4*)(vp);         // 512B contiguous wave-loads
        half4 af1 = *(const half4*)(vp + 256);
        half4 af2 = *(const half4*)(vp + 512);
        half4 af3 = *(const half4*)(vp + 768);
        __builtin_amdgcn_s_setprio(1);
        ac0 = __builtin_amdgcn_mfma_f32_16x16x16f16(af0, ep, ac0, 0, 0, 0);
        ac1 = __builtin_amdgcn_mfma_f32_16x16x16f16(af1, ep, ac1, 0, 0, 0);
        ac2 = __builtin_amdgcn_mfma_f32_16x16x16f16(af2, ep, ac2, 0, 0, 0);
        ac3 = __builtin_amdgcn_mfma_f32_16x16x16f16(af3, ep, ac3, 0, 0, 0);
        __builtin_amdgcn_s_setprio(0);
    }
    ps += __shfl_xor(ps, 16);
    ps += __shfl_xor(ps, 32);
    if (lp == 0) sums8[w][lm] = ps;        // plain store, unique slot
    wg_barrier_lds();                       // sums8 + own trans writes visible

    // ---- phase 2: per-row 1KB single-segment PLAIN score stores ----
    {
        float s = 0.0f;
#pragma unroll
        for (int ww = 0; ww < 8; ++ww) s += sums8[ww][lm];   // fixed order
        float iv = (s > 0.0f) ? (1.0f / s) : 0.0f;           // iv for q-row = lm
        float* sbase = score + ((size_t)bh * NS + q0) * NS + w * 256;
#pragma unroll
        for (int r = 0; r < 16; ++r) {
            float ivr = __shfl(iv, r);       // row r's inverse (lane r broadcast)
            half4 hv = *(const half4*)(tw + r * TPH + l * 4);   // ds_read_b64
            float4v f;
            f[0] = (float)hv[0] * ivr;
            f[1] = (float)hv[1] * ivr;
            f[2] = (float)hv[2] * ivr;
            f[3] = (float)hv[3] * ivr;
            // 64 lanes x 16B = 1KB fully contiguous, full lines, PLAIN store
            *(float4v*)(sbase + (size_t)r * NS + l * 4) = f;
        }
    }
    // trans slice is dead; reuse it for outb. Guard: own ds_reads complete,
    // and forbid the compiler from hoisting the writes above the reads.
    asm volatile("s_waitcnt lgkmcnt(0)" ::: "memory");
    __builtin_amdgcn_sched_barrier(0);

    // per-wave outb slices (C-frag: q = lm cols, d_local = lp*4 + reg)
    {
        float* ow = (float*)tw + lm * 64 + lp * 4;   // 4KB used of 8.4KB slice
#pragma unroll
        for (int r = 0; r < 4; ++r) {
            ow[ 0 + r] = ac0[r];
            ow[16 + r] = ac1[r];
            ow[32 + r] = ac2[r];
            ow[48 + r] = ac3[r];
        }
    }
    wg_barrier_lds();   // outb visible (score stores still in flight)

    // ---- phase 3: out = (sum of 8 wave slices) * invs (nt) ----
    {
        float* orow = out + ((size_t)bh * NS + q0) * ND;
        for (int i = tid; i < 16 * 64; i += TPB) {
            int r = i >> 6;
            float s = 0.0f;
#pragma unroll
            for (int ww = 0; ww < 8; ++ww) s += sums8[ww][r];  // fixed order
            float iv = (s > 0.0f) ? (1.0f / s) : 0.0f;
            float acc = 0.0f;
#pragma unroll
            for (int ww = 0; ww < 8; ++ww)
                acc += ((const float*)(pool + ww * WSLICE))[i];
            __builtin_nontemporal_store(acc * iv, &orow[i]);
        }
    }
}

// ---------------------------------------------------------------------------
extern "C" void kernel_launch(void* const* d_in, const int* in_sizes, int n_in,
                              void* d_out, int out_size, void* d_ws, size_t ws_size,
                              hipStream_t stream) {
    const float* q    = (const float*)d_in[0];
    const float* k    = (const float*)d_in[1];
    const float* v    = (const float*)d_in[2];
    const int*   mask = (const int*)d_in[3];

    float* out   = (float*)d_out;            // [B,H,S,D]
    float* score = out + (size_t)NE;         // [B,H,S,S]

    _Float16* qrw = (_Float16*)d_ws;
    _Float16* kr6 = qrw + NE;
    _Float16* v4w = kr6 + NE;
    unsigned int* mp = (unsigned int*)(v4w + NE);   // NB*NS*NS/32 words = 1 MB

    prep_kernel<<<dim3(ROPE_BLKS + VT_BLKS + MP_BLKS), dim3(256), 0, stream>>>(
        q, k, v, mask, qrw, kr6, v4w, mp);
    attn_reg_kernel<<<dim3(NB * NH * (NS / 16)), dim3(TPB), 0, stream>>>(
        qrw, kr6, v4w, mp, out, score);
}

// Round 21
// 201.242 us; speedup vs baseline: 1.0369x; 1.0369x over previous
//
#include <hip/hip_runtime.h>
#include <hip/hip_fp16.h>

// Shapes (fixed by the reference setup_inputs)
#define NB 2
#define NH 16
#define NS 2048
#define ND 64

typedef __attribute__((ext_vector_type(8))) _Float16 half8;
typedef __attribute__((ext_vector_type(4))) _Float16 half4;
typedef __attribute__((ext_vector_type(4))) float float4v;

static constexpr int NE  = NB * NH * NS * ND;    // 4,194,304 elems per tensor
static constexpr int TPB = 512;                  // 8 waves

// LDS-only workgroup barrier (R14-verified): syncs LDS without vmcnt drain.
__device__ __forceinline__ void wg_barrier_lds() {
    asm volatile("s_waitcnt lgkmcnt(0)" ::: "memory");
    __builtin_amdgcn_s_barrier();
    __builtin_amdgcn_sched_barrier(0);
}

// ---------------------------------------------------------------------------
// Fused prep kernel (R15/R16-verified, unchanged).
// kr6 (per bh): [kt][oct=d/8][key%16][d%8] -> QK^T B-frag load 1024B contig.
// v4  (per bh): [kt][dblk=d/16][kq][d%16][key%4] -> PV A-frag load 512B contig.
// ---------------------------------------------------------------------------
static constexpr int ROPE_BLKS = (NE / 2) / 256;          // 8192
static constexpr int VT_BLKS   = NE / 256;                // 16384
static constexpr int MP_BLKS   = (NB * NS * NS) / 256;    // 32768

__global__ void prep_kernel(const float* __restrict__ q,
                            const float* __restrict__ k,
                            const float* __restrict__ v,
                            const int* __restrict__ mask,
                            _Float16* __restrict__ qr,
                            _Float16* __restrict__ kr6,
                            _Float16* __restrict__ v4,
                            unsigned int* __restrict__ mp) {
    int blk = blockIdx.x;
    if (blk < ROPE_BLKS) {
        int idx = blk * 256 + threadIdx.x;          // over NE/2
        int i   = idx & 31;
        int row = idx >> 5;
        int s   = row & (NS - 1);
        int bh  = row >> 11;

        float inv_freq = expf((float)i * -0.2878231366242710f);  // 10000^(-i/32)
        float ang = (float)s * inv_freq;
        float sn, cs;
        sincosf(ang, &sn, &cs);

        size_t base = (size_t)row * ND + 2 * i;
        float q0 = q[base], q1 = q[base + 1];
        float k0 = k[base], k1 = k[base + 1];
        qr[base]     = (_Float16)(q0 * cs - q1 * sn);
        qr[base + 1] = (_Float16)(q1 * cs + q0 * sn);

        int oct = i >> 2;
        int j0  = (2 * i) & 7;
        size_t t6 = ((size_t)(bh * 128 + (s >> 4)) * 8 + oct) * 128 + (s & 15) * 8 + j0;
        kr6[t6]     = (_Float16)(k0 * cs - k1 * sn);
        kr6[t6 + 1] = (_Float16)(k1 * cs + k0 * sn);
    } else if (blk < ROPE_BLKS + VT_BLKS) {
        int idx = (blk - ROPE_BLKS) * 256 + threadIdx.x;
        int j    = idx & 3;
        int lm   = (idx >> 2) & 15;
        int kq   = (idx >> 6) & 3;
        int dblk = (idx >> 8) & 3;
        int kt   = (idx >> 10) & 127;
        int bh   = idx >> 17;
        int key  = kt * 16 + kq * 4 + j;
        int d    = dblk * 16 + lm;
        v4[idx] = (_Float16)v[((size_t)bh * NS + key) * ND + d];
    } else {
        size_t idx = (size_t)(blk - ROPE_BLKS - VT_BLKS) * 256 + threadIdx.x;
        unsigned long long bal = __ballot(mask[idx] != 0);
        int l = threadIdx.x & 63;
        if (l == 0)       mp[idx >> 5] = (unsigned int)bal;
        else if (l == 32) mp[idx >> 5] = (unsigned int)(bal >> 32);
    }
}

// ---------------------------------------------------------------------------
// Pipelined attention kernel (R21). One WG = 8 waves = 8 consecutive q-tiles,
// software-pipelined: while phase-1 of tile i runs {K,QK^T,exp,stage,V,PV},
// ONE 1KB nt row-store of tile i-1's score issues per key-tile iteration ->
// loads and stores co-issue continuously (R19's serial phases: 61us loads +
// 82us stores per CU; overlapped target ~max(61,82)).
// Stores placed LAST in iteration program order so vmcnt load-waits don't
// queue behind older stores. Double-buffered trans/maskb/sums8 (ping-pong).
// 144,384 B dynamic LDS -> 1 WG/CU (8 waves).
// DETERMINISM: no LDS atomics/init; unique-owner writes before barriers;
// fixed-order sums. Numerics identical to R19 (same fp16 e rounding).
// ---------------------------------------------------------------------------
static constexpr int TPH     = 264;         // trans pitch in halfs (528 B)
static constexpr int WSLICE  = 16 * TPH;    // halfs per wave slice (8448 B)
static constexpr int T_TILES = 8;           // q-tiles per WG
static constexpr int TRANS_B = 2 * 8 * WSLICE * 2;        // 135,168
static constexpr int MASK_OFF = TRANS_B;                   // maskb[2][16][64]
static constexpr int SUMS_OFF = TRANS_B + 8192;            // sums8[2][8][16]
static constexpr int LDS_BYTES = SUMS_OFF + 1024;          // 144,384

// One tile body. I may be runtime (buffer parity via I&1); CUR/PREV are
// static register-array names (rule #20). DOPREV/DOPREF are compile-time.
#define TILE_BODY(I, CUR, PREV, DOPREV, DOPREF)                                 \
  do {                                                                          \
    const int i_   = (I);                                                       \
    const int cb_  = i_ & 1, pb_ = cb_ ^ 1;                                     \
    const int q0c_ = q00 + i_ * 16;                                             \
    const int q0p_ = q00 + (i_ - 1) * 16;                                       \
    _Float16* twc = trans + (size_t)(cb_ * 8 + w) * WSLICE;                     \
    _Float16* twp = trans + (size_t)(pb_ * 8 + w) * WSLICE;                     \
    const _Float16* qrow = qr + ((size_t)bh * NS + q0c_ + lm) * ND;             \
    half8 a0 = *(const half8*)(qrow + lp * 8);                                  \
    half8 a1 = *(const half8*)(qrow + 32 + lp * 8);                             \
    _Pragma("unroll") for (int r = 0; r < 4; ++r)                               \
        CUR[r] = (float4v){0.f, 0.f, 0.f, 0.f};                                 \
    float ivp = 0.0f;                                                           \
    if (DOPREV) {                                                               \
      float s_ = 0.0f;                                                          \
      _Pragma("unroll") for (int ww = 0; ww < 8; ++ww)                          \
          s_ += sums8[pb_ * 128 + ww * 16 + lm];                                \
      ivp = (s_ > 0.0f) ? (1.0f / s_) : 0.0f;                                   \
    }                                                                           \
    float* sprev = score + ((size_t)bh * NS + q0p_) * NS + w * 256;             \
    float ps = 0.0f;                                                            \
    _Pragma("unroll 4")                                                         \
    for (int t = 0; t < 16; ++t) {                                              \
      int kt = w * 16 + t;                                                      \
      const _Float16* kp = k6 + (size_t)kt * 1024 + l * 8;                      \
      half8 b0 = *(const half8*)(kp);                                           \
      half8 b1 = *(const half8*)(kp + 512);                                     \
      const _Float16* vp = vb + (size_t)kt * 1024;                              \
      half4 af0 = *(const half4*)(vp);                                          \
      half4 af1 = *(const half4*)(vp + 256);                                    \
      half4 af2 = *(const half4*)(vp + 512);                                    \
      half4 af3 = *(const half4*)(vp + 768);                                    \
      float4v acc = {0.f, 0.f, 0.f, 0.f};                                       \
      acc = __builtin_amdgcn_mfma_f32_16x16x32_f16(b0, a0, acc, 0, 0, 0);       \
      acc = __builtin_amdgcn_mfma_f32_16x16x32_f16(b1, a1, acc, 0, 0, 0);       \
      int keyb = kt * 16 + lp * 4;                                              \
      unsigned int mw = maskb[cb_ * 1024 + lm * 64 + (keyb >> 5)];              \
      int bit0 = keyb & 31;                                                     \
      half4 ep;                                                                 \
      _Pragma("unroll") for (int r = 0; r < 4; ++r) {                           \
        float ev = ((mw >> (bit0 + r)) & 1u) ? __expf(acc[r] * 0.125f) : 0.0f;  \
        ps += ev;                                                               \
        ep[r] = (_Float16)ev;                                                   \
      }                                                                         \
      *(half4*)(twc + lm * TPH + t * 16 + lp * 4) = ep;                         \
      __builtin_amdgcn_s_setprio(1);                                            \
      CUR[0] = __builtin_amdgcn_mfma_f32_16x16x16f16(af0, ep, CUR[0], 0, 0, 0); \
      CUR[1] = __builtin_amdgcn_mfma_f32_16x16x16f16(af1, ep, CUR[1], 0, 0, 0); \
      CUR[2] = __builtin_amdgcn_mfma_f32_16x16x16f16(af2, ep, CUR[2], 0, 0, 0); \
      CUR[3] = __builtin_amdgcn_mfma_f32_16x16x16f16(af3, ep, CUR[3], 0, 0, 0); \
      __builtin_amdgcn_s_setprio(0);                                            \
      if (DOPREV) {   /* interleaved 1KB nt row-store of prev tile */           \
        float ivr = __shfl(ivp, t);                                             \
        half4 hv = *(const half4*)(twp + t * TPH + l * 4);                      \
        float4v f_;                                                             \
        f_[0] = (float)hv[0] * ivr; f_[1] = (float)hv[1] * ivr;                 \
        f_[2] = (float)hv[2] * ivr; f_[3] = (float)hv[3] * ivr;                 \
        __builtin_nontemporal_store(f_, (float4v*)(sprev + (size_t)t * NS + l * 4)); \
      }                                                                         \
    }                                                                           \
    if (DOPREF) {     /* prefetch next tile's packed mask into maskb[pb] */     \
      const unsigned int* mnext = mp + ((size_t)b * NS + q00 + (i_ + 1) * 16) * 64; \
      for (int j = tid; j < 1024; j += TPB) maskb[pb_ * 1024 + j] = mnext[j];   \
    }                                                                           \
    ps += __shfl_xor(ps, 16);                                                   \
    ps += __shfl_xor(ps, 32);                                                   \
    if (lp == 0) sums8[cb_ * 128 + w * 16 + lm] = ps;                           \
    if (DOPREV) {     /* outb(prev) into dead twp (wave-private; lgkm guard) */ \
      asm volatile("s_waitcnt lgkmcnt(0)" ::: "memory");                        \
      __builtin_amdgcn_sched_barrier(0);                                        \
      float* ow = (float*)twp + lm * 64 + lp * 4;                               \
      _Pragma("unroll") for (int r = 0; r < 4; ++r) {                           \
        ow[ 0 + r] = PREV[0][r]; ow[16 + r] = PREV[1][r];                       \
        ow[32 + r] = PREV[2][r]; ow[48 + r] = PREV[3][r];                       \
      }                                                                         \
    }                                                                           \
    wg_barrier_lds();                                                           \
    if (DOPREV) {     /* out(prev) from the 8 wave slices, fixed order */       \
      float* orow = out + ((size_t)bh * NS + q0p_) * ND;                        \
      for (int j = tid; j < 1024; j += TPB) {                                   \
        int r_ = j >> 6;                                                        \
        float s_ = 0.0f;                                                        \
        _Pragma("unroll") for (int ww = 0; ww < 8; ++ww)                        \
            s_ += sums8[pb_ * 128 + ww * 16 + r_];                              \
        float iv_ = (s_ > 0.0f) ? (1.0f / s_) : 0.0f;                           \
        float a_ = 0.0f;                                                        \
        _Pragma("unroll") for (int ww = 0; ww < 8; ++ww)                        \
            a_ += ((const float*)(trans + (size_t)(pb_ * 8 + ww) * WSLICE))[j]; \
        __builtin_nontemporal_store(a_ * iv_, &orow[j]);                        \
      }                                                                         \
      wg_barrier_lds();   /* out-reads done before next body stages into pb */  \
    }                                                                           \
  } while (0)

__global__ __launch_bounds__(TPB, 2)
void attn_pipe_kernel(const _Float16* __restrict__ qr,
                      const _Float16* __restrict__ kr6,
                      const _Float16* __restrict__ v4,
                      const unsigned int* __restrict__ mp,
                      float* __restrict__ out,
                      float* __restrict__ score) {
    extern __shared__ char lds_raw[];
    _Float16*     trans = (_Float16*)lds_raw;                 // [2][8][16][TPH]
    unsigned int* maskb = (unsigned int*)(lds_raw + MASK_OFF);// [2][16][64]
    float*        sums8 = (float*)(lds_raw + SUMS_OFF);       // [2][8][16]

    // XCD-aware bijective swizzle: 512 WGs -> contiguous 64 per XCD
    int wgid = (blockIdx.x & 7) * 64 + (blockIdx.x >> 3);
    int g0  = wgid * T_TILES;            // first global q-tile
    int bh  = g0 >> 7;
    int b   = bh >> 4;
    int q00 = (g0 & 127) * 16;           // first q-row (all 8 tiles in same bh)

    int tid = threadIdx.x;
    int w   = tid >> 6;
    int l   = tid & 63;
    int lm  = l & 15;
    int lp  = l >> 4;

    const _Float16* k6 = kr6 + (size_t)bh * 128 * 1024;
    const _Float16* vb = v4 + (size_t)bh * 128 * 1024 + l * 4;

    // prologue: mask for tile 0
    {
        const unsigned int* m0 = mp + ((size_t)b * NS + q00) * 64;
        for (int j = tid; j < 1024; j += TPB) maskb[j] = m0[j];
    }
    wg_barrier_lds();

    float4v accA[4], accB[4];
    TILE_BODY(0, accA, accB, false, true);
#pragma unroll 1
    for (int i = 1; i <= 5; i += 2) {
        TILE_BODY(i,     accB, accA, true, true);
        TILE_BODY(i + 1, accA, accB, true, true);
    }
    TILE_BODY(7, accB, accA, true, false);

    // epilogue: tile 7 (parity 1, acc = accB): bunched stores + outb + out
    {
        const int pb_ = 1;
        const int q0p_ = q00 + 7 * 16;
        _Float16* twp = trans + (size_t)(pb_ * 8 + w) * WSLICE;
        float s_ = 0.0f;
#pragma unroll
        for (int ww = 0; ww < 8; ++ww) s_ += sums8[pb_ * 128 + ww * 16 + lm];
        float ivp = (s_ > 0.0f) ? (1.0f / s_) : 0.0f;
        float* sprev = score + ((size_t)bh * NS + q0p_) * NS + w * 256;
#pragma unroll 4
        for (int t = 0; t < 16; ++t) {
            float ivr = __shfl(ivp, t);
            half4 hv = *(const half4*)(twp + t * TPH + l * 4);
            float4v f_;
            f_[0] = (float)hv[0] * ivr; f_[1] = (float)hv[1] * ivr;
            f_[2] = (float)hv[2] * ivr; f_[3] = (float)hv[3] * ivr;
            __builtin_nontemporal_store(f_, (float4v*)(sprev + (size_t)t * NS + l * 4));
        }
        asm volatile("s_waitcnt lgkmcnt(0)" ::: "memory");
        __builtin_amdgcn_sched_barrier(0);
        float* ow = (float*)twp + lm * 64 + lp * 4;
#pragma unroll
        for (int r = 0; r < 4; ++r) {
            ow[ 0 + r] = accB[0][r]; ow[16 + r] = accB[1][r];
            ow[32 + r] = accB[2][r]; ow[48 + r] = accB[3][r];
        }
        wg_barrier_lds();
        float* orow = out + ((size_t)bh * NS + q0p_) * ND;
        for (int j = tid; j < 1024; j += TPB) {
            int r_ = j >> 6;
            float ss = 0.0f;
#pragma unroll
            for (int ww = 0; ww < 8; ++ww) ss += sums8[pb_ * 128 + ww * 16 + r_];
            float iv_ = (ss > 0.0f) ? (1.0f / ss) : 0.0f;
            float a_ = 0.0f;
#pragma unroll
            for (int ww = 0; ww < 8; ++ww)
                a_ += ((const float*)(trans + (size_t)(pb_ * 8 + ww) * WSLICE))[j];
            __builtin_nontemporal_store(a_ * iv_, &orow[j]);
        }
    }
}

// ---------------------------------------------------------------------------
extern "C" void kernel_launch(void* const* d_in, const int* in_sizes, int n_in,
                              void* d_out, int out_size, void* d_ws, size_t ws_size,
                              hipStream_t stream) {
    const float* q    = (const float*)d_in[0];
    const float* k    = (const float*)d_in[1];
    const float* v    = (const float*)d_in[2];
    const int*   mask = (const int*)d_in[3];

    float* out   = (float*)d_out;            // [B,H,S,D]
    float* score = out + (size_t)NE;         // [B,H,S,S]

    _Float16* qrw = (_Float16*)d_ws;
    _Float16* kr6 = qrw + NE;
    _Float16* v4w = kr6 + NE;
    unsigned int* mp = (unsigned int*)(v4w + NE);   // 1 MB

    static_assert(LDS_BYTES <= 160 * 1024, "LDS budget");
    (void)hipFuncSetAttribute(reinterpret_cast<const void*>(&attn_pipe_kernel),
                              hipFuncAttributeMaxDynamicSharedMemorySize, LDS_BYTES);

    prep_kernel<<<dim3(ROPE_BLKS + VT_BLKS + MP_BLKS), dim3(256), 0, stream>>>(
        q, k, v, mask, qrw, kr6, v4w, mp);
    attn_pipe_kernel<<<dim3(NB * NH * (NS / 16) / T_TILES), dim3(TPB), LDS_BYTES, stream>>>(
        qrw, kr6, v4w, mp, out, score);
}

// Round 22
// 196.676 us; speedup vs baseline: 1.0609x; 1.0232x over previous
//
#include <hip/hip_runtime.h>
#include <hip/hip_fp16.h>

// Shapes (fixed by the reference setup_inputs)
#define NB 2
#define NH 16
#define NS 2048
#define ND 64

typedef __attribute__((ext_vector_type(8))) _Float16 half8;
typedef __attribute__((ext_vector_type(4))) _Float16 half4;
typedef __attribute__((ext_vector_type(4))) float float4v;

static constexpr int NE  = NB * NH * NS * ND;    // 4,194,304 elems per tensor
static constexpr int TPB = 512;                  // 8 waves

// LDS-only workgroup barrier (R14-verified): syncs LDS without vmcnt drain.
__device__ __forceinline__ void wg_barrier_lds() {
    asm volatile("s_waitcnt lgkmcnt(0)" ::: "memory");
    __builtin_amdgcn_s_barrier();
    __builtin_amdgcn_sched_barrier(0);
}
// Wave-local LDS RAW/WAR guard (own ds ops retired; no hoisting).
__device__ __forceinline__ void wave_lds_guard() {
    asm volatile("s_waitcnt lgkmcnt(0)" ::: "memory");
    __builtin_amdgcn_sched_barrier(0);
}

// ---------------------------------------------------------------------------
// Fused prep kernel (R15/R16-verified, unchanged).
// kr6 (per bh): [kt][oct=d/8][key%16][d%8] -> QK^T B-frag load 1024B contig.
// v4  (per bh): [kt][dblk=d/16][kq][d%16][key%4] -> PV A-frag load 512B contig.
// ---------------------------------------------------------------------------
static constexpr int ROPE_BLKS = (NE / 2) / 256;          // 8192
static constexpr int VT_BLKS   = NE / 256;                // 16384
static constexpr int MP_BLKS   = (NB * NS * NS) / 256;    // 32768

__global__ void prep_kernel(const float* __restrict__ q,
                            const float* __restrict__ k,
                            const float* __restrict__ v,
                            const int* __restrict__ mask,
                            _Float16* __restrict__ qr,
                            _Float16* __restrict__ kr6,
                            _Float16* __restrict__ v4,
                            unsigned int* __restrict__ mp) {
    int blk = blockIdx.x;
    if (blk < ROPE_BLKS) {
        int idx = blk * 256 + threadIdx.x;          // over NE/2
        int i   = idx & 31;
        int row = idx >> 5;
        int s   = row & (NS - 1);
        int bh  = row >> 11;

        float inv_freq = expf((float)i * -0.2878231366242710f);  // 10000^(-i/32)
        float ang = (float)s * inv_freq;
        float sn, cs;
        sincosf(ang, &sn, &cs);

        size_t base = (size_t)row * ND + 2 * i;
        float q0 = q[base], q1 = q[base + 1];
        float k0 = k[base], k1 = k[base + 1];
        qr[base]     = (_Float16)(q0 * cs - q1 * sn);
        qr[base + 1] = (_Float16)(q1 * cs + q0 * sn);

        int oct = i >> 2;
        int j0  = (2 * i) & 7;
        size_t t6 = ((size_t)(bh * 128 + (s >> 4)) * 8 + oct) * 128 + (s & 15) * 8 + j0;
        kr6[t6]     = (_Float16)(k0 * cs - k1 * sn);
        kr6[t6 + 1] = (_Float16)(k1 * cs + k0 * sn);
    } else if (blk < ROPE_BLKS + VT_BLKS) {
        int idx = (blk - ROPE_BLKS) * 256 + threadIdx.x;
        int j    = idx & 3;
        int lm   = (idx >> 2) & 15;
        int kq   = (idx >> 6) & 3;
        int dblk = (idx >> 8) & 3;
        int kt   = (idx >> 10) & 127;
        int bh   = idx >> 17;
        int key  = kt * 16 + kq * 4 + j;
        int d    = dblk * 16 + lm;
        v4[idx] = (_Float16)v[((size_t)bh * NS + key) * ND + d];
    } else {
        size_t idx = (size_t)(blk - ROPE_BLKS - VT_BLKS) * 256 + threadIdx.x;
        unsigned long long bal = __ballot(mask[idx] != 0);
        int l = threadIdx.x & 63;
        if (l == 0)       mp[idx >> 5] = (unsigned int)bal;
        else if (l == 32) mp[idx >> 5] = (unsigned int)(bal >> 32);
    }
}

// ---------------------------------------------------------------------------
// Attention kernel (R22): 32 q-rows per WG, K/V loaded ONCE per key-tile.
// Each wave owns keys [w*256,+256) and computes TWO 16-row q-subtiles:
//   A: e staged to wave-private LDS (R19 path), B: e kept in earrB regs.
// -> kr6/v4 L2 traffic halves (2.1 GB -> 1.05 GB, ~61 -> ~30 us/chip).
// Phase 2: store A rows (1KB nt), re-stage B through the SAME trans slice
// (wave-local guards), store B rows. LDS 76.8 KB -> 2 WG/CU kept.
// DETERMINISM: no LDS atomics/init; unique-owner writes before barriers;
// fixed-order sums. Numerics: e rounds through fp16 as in R16/R19.
// ---------------------------------------------------------------------------
static constexpr int TPH    = 264;        // trans pitch in halfs (528 B)
static constexpr int WSLICE = 16 * TPH;   // halfs per wave slice (8448 B)

__global__ __launch_bounds__(TPB, 4)
void attn_reg_kernel(const _Float16* __restrict__ qr,
                     const _Float16* __restrict__ kr6,
                     const _Float16* __restrict__ v4,
                     const unsigned int* __restrict__ mp,
                     float* __restrict__ out,
                     float* __restrict__ score) {
    __shared__ unsigned int maskb[32 * 64];        // 8 KB
    __shared__ float        sumsA[8][16];          // 512 B
    __shared__ float        sumsB[8][16];          // 512 B
    __shared__ _Float16     pool[8 * WSLICE];      // 67,584 B (trans, outb alias)

    // XCD-aware bijective swizzle: 2048 WGs -> contiguous 256 per XCD
    int wgid = (blockIdx.x & 7) * 256 + (blockIdx.x >> 3);
    int qt = wgid & 63;
    int bh = wgid >> 6;
    int b  = bh >> 4;
    int q0 = qt * 32;

    int tid = threadIdx.x;
    int w   = tid >> 6;
    int l   = tid & 63;
    int lm  = l & 15;
    int lp  = l >> 4;

    {
        const unsigned int* mrow = mp + ((size_t)b * NS + q0) * 64;
        for (int i = tid; i < 32 * 64; i += TPB) maskb[i] = mrow[i];
    }

    // Q B-fragments for both subtiles (col n = q, k-slice d = lp*8 (+32))
    const _Float16* qrowA = qr + ((size_t)bh * NS + q0 + lm) * ND;
    const _Float16* qrowB = qrowA + 16 * ND;
    half8 a0A = *(const half8*)(qrowA + lp * 8);
    half8 a1A = *(const half8*)(qrowA + 32 + lp * 8);
    half8 a0B = *(const half8*)(qrowB + lp * 8);
    half8 a1B = *(const half8*)(qrowB + 32 + lp * 8);
    const _Float16* k6 = kr6 + (size_t)bh * 128 * 1024;
    const _Float16* vb = v4 + (size_t)bh * 128 * 1024 + l * 4;
    _Float16* tw = pool + w * WSLICE;               // wave-private trans slice
    wg_barrier_lds();                      // maskb visible

    // ---- phase 1: shared K/V loads; QK^T+exp+PV for BOTH subtiles ----
    float4v acA0 = {0.f, 0.f, 0.f, 0.f}, acA1 = {0.f, 0.f, 0.f, 0.f};
    float4v acA2 = {0.f, 0.f, 0.f, 0.f}, acA3 = {0.f, 0.f, 0.f, 0.f};
    float4v acB0 = {0.f, 0.f, 0.f, 0.f}, acB1 = {0.f, 0.f, 0.f, 0.f};
    float4v acB2 = {0.f, 0.f, 0.f, 0.f}, acB3 = {0.f, 0.f, 0.f, 0.f};
    half4 earrB[16];
    float psA = 0.0f, psB = 0.0f;
#pragma unroll
    for (int t = 0; t < 16; ++t) {
        int kt = w * 16 + t;
        const _Float16* kp = k6 + (size_t)kt * 1024 + l * 8;
        half8 b0 = *(const half8*)(kp);          // 1024B contiguous (shared A+B)
        half8 b1 = *(const half8*)(kp + 512);
        float4v sa = {0.f, 0.f, 0.f, 0.f};
        float4v sb = {0.f, 0.f, 0.f, 0.f};
        sa = __builtin_amdgcn_mfma_f32_16x16x32_f16(b0, a0A, sa, 0, 0, 0);
        sa = __builtin_amdgcn_mfma_f32_16x16x32_f16(b1, a1A, sa, 0, 0, 0);
        sb = __builtin_amdgcn_mfma_f32_16x16x32_f16(b0, a0B, sb, 0, 0, 0);
        sb = __builtin_amdgcn_mfma_f32_16x16x32_f16(b1, a1B, sb, 0, 0, 0);
        // key = kt*16 + lp*4 + r ; qA = q0+lm ; qB = q0+16+lm
        int keyb = kt * 16 + lp * 4;
        int word = keyb >> 5;
        int bit0 = keyb & 31;
        unsigned int mwA = maskb[lm * 64 + word];
        unsigned int mwB = maskb[(lm + 16) * 64 + word];
        half4 epA, epB;
#pragma unroll
        for (int r = 0; r < 4; ++r) {
            float evA = ((mwA >> (bit0 + r)) & 1u) ? __expf(sa[r] * 0.125f) : 0.0f;
            float evB = ((mwB >> (bit0 + r)) & 1u) ? __expf(sb[r] * 0.125f) : 0.0f;
            psA += evA; psB += evB;
            epA[r] = (_Float16)evA;
            epB[r] = (_Float16)evB;
        }
        *(half4*)(tw + lm * TPH + t * 16 + lp * 4) = epA;   // stage A
        earrB[t] = epB;                                      // keep B in regs
        // PV (V loaded once, used by both subtiles)
        const _Float16* vp = vb + (size_t)kt * 1024;
        half4 af0 = *(const half4*)(vp);
        half4 af1 = *(const half4*)(vp + 256);
        half4 af2 = *(const half4*)(vp + 512);
        half4 af3 = *(const half4*)(vp + 768);
        __builtin_amdgcn_s_setprio(1);
        acA0 = __builtin_amdgcn_mfma_f32_16x16x16f16(af0, epA, acA0, 0, 0, 0);
        acA1 = __builtin_amdgcn_mfma_f32_16x16x16f16(af1, epA, acA1, 0, 0, 0);
        acA2 = __builtin_amdgcn_mfma_f32_16x16x16f16(af2, epA, acA2, 0, 0, 0);
        acA3 = __builtin_amdgcn_mfma_f32_16x16x16f16(af3, epA, acA3, 0, 0, 0);
        acB0 = __builtin_amdgcn_mfma_f32_16x16x16f16(af0, epB, acB0, 0, 0, 0);
        acB1 = __builtin_amdgcn_mfma_f32_16x16x16f16(af1, epB, acB1, 0, 0, 0);
        acB2 = __builtin_amdgcn_mfma_f32_16x16x16f16(af2, epB, acB2, 0, 0, 0);
        acB3 = __builtin_amdgcn_mfma_f32_16x16x16f16(af3, epB, acB3, 0, 0, 0);
        __builtin_amdgcn_s_setprio(0);
    }
    psA += __shfl_xor(psA, 16);
    psA += __shfl_xor(psA, 32);
    psB += __shfl_xor(psB, 16);
    psB += __shfl_xor(psB, 32);
    if (lp == 0) { sumsA[w][lm] = psA; sumsB[w][lm] = psB; }
    wg_barrier_lds();                       // sums + trans(A) visible

    // ---- phase 2A: subtile A score rows (1KB single-segment nt stores) ----
    {
        float s = 0.0f;
#pragma unroll
        for (int ww = 0; ww < 8; ++ww) s += sumsA[ww][lm];   // fixed order
        float iv = (s > 0.0f) ? (1.0f / s) : 0.0f;
        float* sbase = score + ((size_t)bh * NS + q0) * NS + w * 256;
#pragma unroll
        for (int r = 0; r < 16; ++r) {
            float ivr = __shfl(iv, r);
            half4 hv = *(const half4*)(tw + r * TPH + l * 4);
            float4v f;
            f[0] = (float)hv[0] * ivr;
            f[1] = (float)hv[1] * ivr;
            f[2] = (float)hv[2] * ivr;
            f[3] = (float)hv[3] * ivr;
            __builtin_nontemporal_store(f, (float4v*)(sbase + (size_t)r * NS + l * 4));
        }
    }
    // re-stage B through the same wave-private slice (reads of A done)
    wave_lds_guard();
#pragma unroll
    for (int t = 0; t < 16; ++t)
        *(half4*)(tw + lm * TPH + t * 16 + lp * 4) = earrB[t];
    wave_lds_guard();

    // ---- phase 2B: subtile B score rows ----
    {
        float s = 0.0f;
#pragma unroll
        for (int ww = 0; ww < 8; ++ww) s += sumsB[ww][lm];   // fixed order
        float iv = (s > 0.0f) ? (1.0f / s) : 0.0f;
        float* sbase = score + ((size_t)bh * NS + q0 + 16) * NS + w * 256;
#pragma unroll
        for (int r = 0; r < 16; ++r) {
            float ivr = __shfl(iv, r);
            half4 hv = *(const half4*)(tw + r * TPH + l * 4);
            float4v f;
            f[0] = (float)hv[0] * ivr;
            f[1] = (float)hv[1] * ivr;
            f[2] = (float)hv[2] * ivr;
            f[3] = (float)hv[3] * ivr;
            __builtin_nontemporal_store(f, (float4v*)(sbase + (size_t)r * NS + l * 4));
        }
    }
    // trans slice dead; reuse for outb (A rows at +0, B rows at +4KB)
    wave_lds_guard();
    {
        float* owA = (float*)tw + lm * 64 + lp * 4;
        float* owB = owA + 1024;
#pragma unroll
        for (int r = 0; r < 4; ++r) {
            owA[ 0 + r] = acA0[r]; owA[16 + r] = acA1[r];
            owA[32 + r] = acA2[r]; owA[48 + r] = acA3[r];
            owB[ 0 + r] = acB0[r]; owB[16 + r] = acB1[r];
            owB[32 + r] = acB2[r]; owB[48 + r] = acB3[r];
        }
    }
    wg_barrier_lds();   // outb visible (score stores still in flight)

    // ---- phase 3: out (32 rows) = sum of 8 wave slices * invs (nt) ----
    {
        float* orow = out + ((size_t)bh * NS + q0) * ND;
        for (int i = tid; i < 32 * 64; i += TPB) {
            int r = i >> 6;                     // wave-uniform per iteration
            float s = 0.0f;
            if (r < 16) {
#pragma unroll
                for (int ww = 0; ww < 8; ++ww) s += sumsA[ww][r];
            } else {
#pragma unroll
                for (int ww = 0; ww < 8; ++ww) s += sumsB[ww][r - 16];
            }
            float iv = (s > 0.0f) ? (1.0f / s) : 0.0f;
            float acc = 0.0f;
#pragma unroll
            for (int ww = 0; ww < 8; ++ww)
                acc += ((const float*)(pool + ww * WSLICE))[i];
            __builtin_nontemporal_store(acc * iv, &orow[i]);
        }
    }
}

// ---------------------------------------------------------------------------
extern "C" void kernel_launch(void* const* d_in, const int* in_sizes, int n_in,
                              void* d_out, int out_size, void* d_ws, size_t ws_size,
                              hipStream_t stream) {
    const float* q    = (const float*)d_in[0];
    const float* k    = (const float*)d_in[1];
    const float* v    = (const float*)d_in[2];
    const int*   mask = (const int*)d_in[3];

    float* out   = (float*)d_out;            // [B,H,S,D]
    float* score = out + (size_t)NE;         // [B,H,S,S]

    _Float16* qrw = (_Float16*)d_ws;
    _Float16* kr6 = qrw + NE;
    _Float16* v4w = kr6 + NE;
    unsigned int* mp = (unsigned int*)(v4w + NE);   // 1 MB

    prep_kernel<<<dim3(ROPE_BLKS + VT_BLKS + MP_BLKS), dim3(256), 0, stream>>>(
        q, k, v, mask, qrw, kr6, v4w, mp);
    attn_reg_kernel<<<dim3(NB * NH * (NS / 32)), dim3(TPB), 0, stream>>>(
        qrw, kr6, v4w, mp, out, score);
}